// Round 16
// baseline (456.357 us; speedup 1.0000x reference)
//
#include <hip/hip_runtime.h>
#include <math.h>

typedef _Float16 f16x8 __attribute__((ext_vector_type(8)));
typedef _Float16 f16x4 __attribute__((ext_vector_type(4)));
typedef float    f32x4 __attribute__((ext_vector_type(4)));

// XOR-swizzled index into a [rows][128] f16 LDS tile (256B rows, no pad).
__device__ __forceinline__ int swz(int row, int k)
{
    return row * 128 + (k ^ ((row & 15) << 3));
}

// ---------------- W preprocess: fragment-major, ALL 3 layers in one launch ----------------
__global__ void wsplit_all(const float* __restrict__ Wa0, const float* __restrict__ Wa1,
                           const float* __restrict__ Wa2, const float* __restrict__ Wb0,
                           const float* __restrict__ Wb1, const float* __restrict__ Wb2,
                           const float* __restrict__ Wc0, const float* __restrict__ Wc1,
                           const float* __restrict__ Wc2,
                           _Float16* __restrict__ D1, _Float16* __restrict__ D2,
                           _Float16* __restrict__ D3)
{
    int layer = blockIdx.y;
    int CHN = (layer == 2) ? 1 : 2;
    int M   = (layer == 2) ? 40 : 128;
    _Float16* dst = (layer == 0) ? D1 : ((layer == 1) ? D2 : D3);
    int total = 3 * CHN * 2 * 2 * 4 * 512;
    int idx = blockIdx.x * 256 + threadIdx.x;
    if (idx >= total) return;
    int e    = idx & 7;
    int lane = (idx >> 3) & 63;
    int kk   = (idx >> 9) & 3;
    int n    = (idx >> 11) & 1;
    int wc   = (idx >> 12) & 1;
    int rest = idx >> 13;
    int ch   = rest % CHN;
    int br   = rest / CHN;
    int col  = ch * 64 + wc * 32 + n * 16 + (lane & 15);
    int k    = kk * 32 + (lane >> 4) * 8 + e;
    const float* W;
    if (layer == 0)      W = (br == 0) ? Wa0 : ((br == 1) ? Wa1 : Wa2);
    else if (layer == 1) W = (br == 0) ? Wb0 : ((br == 1) ? Wb1 : Wb2);
    else                 W = (br == 0) ? Wc0 : ((br == 1) ? Wc1 : Wc2);
    float v = (col < M) ? W[(size_t)k * M + col] : 0.f;
    _Float16 h = (_Float16)v;
    dst[idx] = h;
    dst[total + idx] = (_Float16)(v - (float)h);
}

// ---------------- split-f16 MFMA GEMM: X in swizzled LDS, W fragment-coalesced from L2 ----
template<int CHN>
__global__ __launch_bounds__(256)
void gemm3(const float* __restrict__ X, const _Float16* __restrict__ Wf,
           const float* __restrict__ b0, const float* __restrict__ b1,
           const float* __restrict__ b2,
           float* __restrict__ out0, _Float16* __restrict__ out1, _Float16* __restrict__ out2,
           int M, int nrows)
{
    __shared__ _Float16 xh[64 * 128], xl[64 * 128];   // 32 KB total

    const int tid  = threadIdx.x;
    const int row0 = blockIdx.x * 64;
    const int ch   = blockIdx.y;
    const int plane = 3 * CHN * 2 * 2 * 4 * 512;

    float4 xr[8];
    #pragma unroll
    for (int i = 0; i < 8; ++i) {
        int idx = tid + i * 256;
        int row = idx >> 5;
        int k   = (idx & 31) * 4;
        int gr  = row0 + row;
        xr[i] = (gr < nrows) ? *(const float4*)(X + (size_t)gr * 128 + k)
                             : make_float4(0.f, 0.f, 0.f, 0.f);
    }
    #pragma unroll
    for (int i = 0; i < 8; ++i) {
        int idx = tid + i * 256;
        int row = idx >> 5;
        int k   = (idx & 31) * 4;
        float vv[4] = {xr[i].x, xr[i].y, xr[i].z, xr[i].w};
        f16x4 h, l;
        #pragma unroll
        for (int j = 0; j < 4; ++j) {
            _Float16 hj = (_Float16)vv[j];
            h[j] = hj;
            l[j] = (_Float16)(vv[j] - (float)hj);
        }
        int o = swz(row, k);
        *(f16x4*)&xh[o] = h;
        *(f16x4*)&xl[o] = l;
    }
    __syncthreads();

    const int lane = tid & 63;
    const int wid  = tid >> 6;
    const int wr   = wid >> 1, wc = wid & 1;
    const int r    = lane & 15, g = lane >> 4;

    f16x8 Ah[2][4], Al[2][4];
    #pragma unroll
    for (int m = 0; m < 2; ++m)
        #pragma unroll
        for (int kk = 0; kk < 4; ++kk) {
            int o = swz(wr * 32 + m * 16 + r, kk * 32 + g * 8);
            Ah[m][kk] = *(const f16x8*)&xh[o];
            Al[m][kk] = *(const f16x8*)&xl[o];
        }

    #pragma unroll
    for (int br = 0; br < 3; ++br) {
        f32x4 acc[2][2];
        #pragma unroll
        for (int m = 0; m < 2; ++m)
            #pragma unroll
            for (int n = 0; n < 2; ++n)
                acc[m][n] = (f32x4){0.f, 0.f, 0.f, 0.f};

        #pragma unroll
        for (int n = 0; n < 2; ++n) {
            size_t fb = ((((size_t)(br * CHN + ch) * 2 + wc) * 2 + n) * 4) * 512 + lane * 8;
            f16x8 Bh[4], Bl[4];
            #pragma unroll
            for (int kk = 0; kk < 4; ++kk) {
                Bh[kk] = *(const f16x8*)&Wf[fb + kk * 512];
                Bl[kk] = *(const f16x8*)&Wf[plane + fb + kk * 512];
            }
            #pragma unroll
            for (int kk = 0; kk < 4; ++kk) {
                #pragma unroll
                for (int m = 0; m < 2; ++m) {
                    acc[m][n] = __builtin_amdgcn_mfma_f32_16x16x32_f16(Ah[m][kk], Bh[kk], acc[m][n], 0, 0, 0);
                    acc[m][n] = __builtin_amdgcn_mfma_f32_16x16x32_f16(Ah[m][kk], Bl[kk], acc[m][n], 0, 0, 0);
                    acc[m][n] = __builtin_amdgcn_mfma_f32_16x16x32_f16(Al[m][kk], Bh[kk], acc[m][n], 0, 0, 0);
                }
            }
        }

        #pragma unroll
        for (int m = 0; m < 2; ++m)
            #pragma unroll
            for (int n = 0; n < 2; ++n) {
                int col = ch * 64 + wc * 32 + n * 16 + r;
                if (col >= M) continue;
                if (br == 0) {
                    float bs = b0[col] + b1[col] + b2[col];
                    #pragma unroll
                    for (int i = 0; i < 4; ++i) {
                        int row = row0 + wr * 32 + m * 16 + g * 4 + i;
                        if (row < nrows)
                            out0[(size_t)row * M + col] = acc[m][n][i] + bs;
                    }
                } else {
                    _Float16* outp = (br == 1) ? out1 : out2;
                    #pragma unroll
                    for (int i = 0; i < 4; ++i) {
                        int row = row0 + wr * 32 + m * 16 + g * 4 + i;
                        if (row < nrows)
                            outp[(size_t)row * M + col] = (_Float16)acc[m][n][i];
                    }
                }
            }
    }
}

// ---------------- combined CSR build over both edge sets (2E edges) ----------------
__global__ void zero_i32(int* __restrict__ p, int n)
{
    int i = blockIdx.x * 256 + threadIdx.x;
    if (i < n) p[i] = 0;
}

__global__ void hist_c(const int* __restrict__ ei1, const int* __restrict__ ei2,
                       int E, int* __restrict__ cnt)
{
    int i = blockIdx.x * 256 + threadIdx.x;
    if (i >= 2 * E) return;
    int d = (i < E) ? ei1[E + i] : ei2[E + (i - E)];
    atomicAdd(&cnt[d], 1);
}

// single-block merged scan: rp = exscan(cnt), rp[N] = total; zero cnt; bincur init.
__global__ __launch_bounds__(256)
void scan_all(int* __restrict__ cnt, int N, int* __restrict__ rp,
              int nbins, int* __restrict__ bincur)
{
    __shared__ int s[256];
    const int tid = threadIdx.x;
    const int chunk = (N + 255) / 256;
    int lo = tid * chunk;
    int hi = lo + chunk; if (hi > N) hi = N;
    if (lo > N) lo = N;
    int sum = 0;
    for (int i = lo; i < hi; ++i) sum += cnt[i];
    s[tid] = sum; __syncthreads();
    for (int off = 1; off < 256; off <<= 1) {
        int t = (tid >= off) ? s[tid - off] : 0;
        __syncthreads();
        s[tid] += t;
        __syncthreads();
    }
    if (tid == 0) rp[N] = s[255];
    int run = tid ? s[tid - 1] : 0;
    for (int i = lo; i < hi; ++i) {
        int c = cnt[i];
        rp[i] = run;
        cnt[i] = 0;                        // reused as binplace cursor
        run += c;
    }
    __threadfence();
    __syncthreads();
    for (int b = tid; b < nbins; b += 256) {
        int r = b << 9;
        bincur[b] = rp[r < N ? r : N];
    }
}

// ---------------- phase C: bin-bucketed staging of edge records ----------------
constexpr int EPB  = 2048;
constexpr int MAXB = 128;

__global__ __launch_bounds__(256)
void binfill(const int* __restrict__ ei1, const float* __restrict__ ew1,
             const int* __restrict__ ei2, const float* __restrict__ ew2,
             int E, int N, int nbins, int* __restrict__ bincur,
             long long* __restrict__ stage, unsigned short* __restrict__ soff)
{
    __shared__ int hist[MAXB];
    __shared__ int scanb[MAXB];
    __shared__ int gbase[MAXB];
    __shared__ long long srec[EPB];
    __shared__ unsigned short sdo[EPB];
    __shared__ unsigned char  sbin[EPB];

    const int t = threadIdx.x;
    const long long base = (long long)blockIdx.x * EPB;
    int total = 2 * E - (int)base; if (total > EPB) total = EPB;

    for (int i = t; i < MAXB; i += 256) hist[i] = 0;
    __syncthreads();

    int myb[8], myr[8], myo[8];
    long long myrec[8];
    #pragma unroll
    for (int k = 0; k < 8; ++k) {
        int i = t + k * 256;
        myb[k] = -1;
        if (i < total) {
            int j = (int)(base + i);
            int set = (j >= E);
            int e = set ? j - E : j;
            const int* ei = set ? ei2 : ei1;
            int d = ei[E + e];
            int s = ei[e] + (set ? N : 0);
            float w = set ? ew2[e] : ew1[e];
            myb[k] = d >> 9;
            myo[k] = d & 511;
            myrec[k] = ((long long)__float_as_int(w) << 32) | (unsigned)s;
            myr[k] = atomicAdd(&hist[myb[k]], 1);
        }
    }
    __syncthreads();

    if (t < MAXB) scanb[t] = hist[t];
    __syncthreads();
    for (int off = 1; off < MAXB; off <<= 1) {
        int tv = 0;
        if (t < MAXB && t >= off) tv = scanb[t - off];
        __syncthreads();
        if (t < MAXB) scanb[t] += tv;
        __syncthreads();
    }
    if (t < nbins && hist[t] > 0)
        gbase[t] = atomicAdd(&bincur[t], hist[t]);
    __syncthreads();

    #pragma unroll
    for (int k = 0; k < 8; ++k) {
        if (myb[k] >= 0) {
            int slot = scanb[myb[k]] - hist[myb[k]] + myr[k];
            srec[slot] = myrec[k];
            sdo[slot]  = (unsigned short)myo[k];
            sbin[slot] = (unsigned char)myb[k];
        }
    }
    __syncthreads();

    #pragma unroll
    for (int k = 0; k < 8; ++k) {
        int i = t + k * 256;
        if (i < total) {
            int b = sbin[i];
            int addr = gbase[b] + (i - (scanb[b] - hist[b]));
            stage[addr] = srec[i];
            soff[addr]  = sdo[i];
        }
    }
}

// ---------------- phase D: within-bin scatter to final CSR slots (L2-local) ----------------
__global__ __launch_bounds__(256)
void binplace(const long long* __restrict__ stage, const unsigned short* __restrict__ soff,
              const int* __restrict__ rp, int N, int* __restrict__ cur,
              long long* __restrict__ pack)
{
    int bin  = blockIdx.x >> 1;
    int half = blockIdx.x & 1;
    int r0 = bin << 9;
    int r1 = r0 + 512; if (r1 > N) r1 = N;
    if (r0 >= N) return;
    int beg = rp[r0], end = rp[r1];
    int mid = beg + ((end - beg + 1) >> 1);
    int lo = half ? mid : beg;
    int hi = half ? end : mid;
    for (int i = lo + threadIdx.x; i < hi; i += 256) {
        long long rec = stage[i];
        int d = r0 + soff[i];
        int p = rp[d] + atomicAdd(&cur[d], 1);
        pack[p] = rec;
    }
}

// ---------------- gather (width 128), 16 lanes/row, f16x8, 4-deep MLP ----------------
__global__ __launch_bounds__(256)
void gather_c128(const _Float16* __restrict__ hc, const int* __restrict__ rp,
                 const long long* __restrict__ pack, float* __restrict__ out, int N)
{
    int row = blockIdx.x * 16 + (threadIdx.x >> 4);
    if (row >= N) return;
    int lane = threadIdx.x & 15;
    int beg = rp[row], end = rp[row + 1];
    float* o = out + (size_t)row * 128 + lane * 8;
    float4 c0 = *(const float4*)o;
    float4 c1 = *(const float4*)(o + 4);
    float a[8] = {};
    int i = beg;
    for (; i + 4 <= end; i += 4) {
        long long q0 = __builtin_nontemporal_load(&pack[i]);
        long long q1 = __builtin_nontemporal_load(&pack[i + 1]);
        long long q2 = __builtin_nontemporal_load(&pack[i + 2]);
        long long q3 = __builtin_nontemporal_load(&pack[i + 3]);
        f16x8 v0 = *(const f16x8*)(hc + (size_t)(unsigned)q0 * 128 + lane * 8);
        f16x8 v1 = *(const f16x8*)(hc + (size_t)(unsigned)q1 * 128 + lane * 8);
        f16x8 v2 = *(const f16x8*)(hc + (size_t)(unsigned)q2 * 128 + lane * 8);
        f16x8 v3 = *(const f16x8*)(hc + (size_t)(unsigned)q3 * 128 + lane * 8);
        float w0 = __int_as_float((int)(q0 >> 32));
        float w1 = __int_as_float((int)(q1 >> 32));
        float w2 = __int_as_float((int)(q2 >> 32));
        float w3 = __int_as_float((int)(q3 >> 32));
        #pragma unroll
        for (int j = 0; j < 8; ++j) {
            a[j] = fmaf(w0, (float)v0[j], a[j]);
            a[j] = fmaf(w1, (float)v1[j], a[j]);
            a[j] = fmaf(w2, (float)v2[j], a[j]);
            a[j] = fmaf(w3, (float)v3[j], a[j]);
        }
    }
    for (; i < end; ++i) {
        long long q0 = __builtin_nontemporal_load(&pack[i]);
        f16x8 v0 = *(const f16x8*)(hc + (size_t)(unsigned)q0 * 128 + lane * 8);
        float w0 = __int_as_float((int)(q0 >> 32));
        #pragma unroll
        for (int j = 0; j < 8; ++j) a[j] = fmaf(w0, (float)v0[j], a[j]);
    }
    c0.x += a[0]; c0.y += a[1]; c0.z += a[2]; c0.w += a[3];
    c1.x += a[4]; c1.y += a[5]; c1.z += a[6]; c1.w += a[7];
    *(float4*)o = c0;
    *(float4*)(o + 4) = c1;
}

// ---------------- final: gather (width 40) + log_softmax fused ----------------
__global__ __launch_bounds__(256)
void gather_ls40(const _Float16* __restrict__ hc, const int* __restrict__ rp,
                 const long long* __restrict__ pack, const float* __restrict__ xlin,
                 float* __restrict__ out, int N)
{
    int row = blockIdx.x * 16 + (threadIdx.x >> 4);
    int lane = threadIdx.x & 15;
    if (row >= N) return;
    bool act = (lane < 10);

    float v0 = -INFINITY, v1 = -INFINITY, v2 = -INFINITY, v3 = -INFINITY;
    if (act) {
        float a0 = 0.f, a1 = 0.f, a2 = 0.f, a3 = 0.f;
        int beg = rp[row], end = rp[row + 1];
        int i = beg;
        for (; i + 4 <= end; i += 4) {
            long long q0 = __builtin_nontemporal_load(&pack[i]);
            long long q1 = __builtin_nontemporal_load(&pack[i + 1]);
            long long q2 = __builtin_nontemporal_load(&pack[i + 2]);
            long long q3 = __builtin_nontemporal_load(&pack[i + 3]);
            f16x4 va = *(const f16x4*)(hc + (size_t)(unsigned)q0 * 40 + lane * 4);
            f16x4 vb = *(const f16x4*)(hc + (size_t)(unsigned)q1 * 40 + lane * 4);
            f16x4 vc = *(const f16x4*)(hc + (size_t)(unsigned)q2 * 40 + lane * 4);
            f16x4 vd = *(const f16x4*)(hc + (size_t)(unsigned)q3 * 40 + lane * 4);
            float wa = __int_as_float((int)(q0 >> 32));
            float wb = __int_as_float((int)(q1 >> 32));
            float wc = __int_as_float((int)(q2 >> 32));
            float wd = __int_as_float((int)(q3 >> 32));
            a0 = fmaf(wa, (float)va[0], a0); a1 = fmaf(wa, (float)va[1], a1);
            a2 = fmaf(wa, (float)va[2], a2); a3 = fmaf(wa, (float)va[3], a3);
            a0 = fmaf(wb, (float)vb[0], a0); a1 = fmaf(wb, (float)vb[1], a1);
            a2 = fmaf(wb, (float)vb[2], a2); a3 = fmaf(wb, (float)vb[3], a3);
            a0 = fmaf(wc, (float)vc[0], a0); a1 = fmaf(wc, (float)vc[1], a1);
            a2 = fmaf(wc, (float)vc[2], a2); a3 = fmaf(wc, (float)vc[3], a3);
            a0 = fmaf(wd, (float)vd[0], a0); a1 = fmaf(wd, (float)vd[1], a1);
            a2 = fmaf(wd, (float)vd[2], a2); a3 = fmaf(wd, (float)vd[3], a3);
        }
        for (; i < end; ++i) {
            long long q0 = __builtin_nontemporal_load(&pack[i]);
            f16x4 va = *(const f16x4*)(hc + (size_t)(unsigned)q0 * 40 + lane * 4);
            float wa = __int_as_float((int)(q0 >> 32));
            a0 = fmaf(wa, (float)va[0], a0); a1 = fmaf(wa, (float)va[1], a1);
            a2 = fmaf(wa, (float)va[2], a2); a3 = fmaf(wa, (float)va[3], a3);
        }
        float4 c = *(const float4*)(xlin + (size_t)row * 40 + lane * 4);
        v0 = c.x + a0; v1 = c.y + a1; v2 = c.z + a2; v3 = c.w + a3;
    }

    float m = fmaxf(fmaxf(v0, v1), fmaxf(v2, v3));
    #pragma unroll
    for (int off = 8; off; off >>= 1) m = fmaxf(m, __shfl_xor(m, off, 16));
    float s = 0.f;
    if (act) s = expf(v0 - m) + expf(v1 - m) + expf(v2 - m) + expf(v3 - m);
    #pragma unroll
    for (int off = 8; off; off >>= 1) s += __shfl_xor(s, off, 16);
    float ls = m + logf(s);

    if (act) {
        float* o = out + (size_t)row * 40 + lane * 4;
        o[0] = v0 - ls; o[1] = v1 - ls; o[2] = v2 - ls; o[3] = v3 - ls;
    }
}

// ---------------- launch ----------------
extern "C" void kernel_launch(void* const* d_in, const int* in_sizes, int n_in,
                              void* d_out, int out_size, void* d_ws, size_t ws_size,
                              hipStream_t stream)
{
    const float* x    = (const float*)d_in[0];
    const int*   ei1  = (const int*)  d_in[1];
    const float* ew1  = (const float*)d_in[2];
    const int*   ei2  = (const int*)  d_in[3];
    const float* ew2  = (const float*)d_in[4];

    const float* W_ln1 = (const float*)d_in[5];   const float* b_ln1 = (const float*)d_in[6];
    const float* W_c11 = (const float*)d_in[7];   const float* b_c11 = (const float*)d_in[8];
    const float* W_c21 = (const float*)d_in[9];   const float* b_c21 = (const float*)d_in[10];
    const float* W_ln2 = (const float*)d_in[11];  const float* b_ln2 = (const float*)d_in[12];
    const float* W_c12 = (const float*)d_in[13];  const float* b_c12 = (const float*)d_in[14];
    const float* W_c22 = (const float*)d_in[15];  const float* b_c22 = (const float*)d_in[16];
    const float* W_ln3 = (const float*)d_in[17];  const float* b_ln3 = (const float*)d_in[18];
    const float* W_c13 = (const float*)d_in[19];  const float* b_c13 = (const float*)d_in[20];
    const float* W_c23 = (const float*)d_in[21];  const float* b_c23 = (const float*)d_in[22];

    const int N = in_sizes[0] / 128;   // 50000
    const int E = in_sizes[2];         // 600000
    const int nbins = (N + 511) >> 9;  // 98

    // ---- workspace layout ----
    auto align_up = [](size_t v) { return (v + 255) & ~(size_t)255; };
    char* base = (char*)d_ws;
    size_t off = 0;
    auto take = [&](size_t bytes) { char* p = base + off; off += align_up(bytes); return p; };

    float*     xA   = (float*)    take((size_t)N * 128 * 4);
    float*     xB   = (float*)    take((size_t)N * 128 * 4);
    _Float16*  hc   = (_Float16*) take((size_t)2 * N * 128 * 2);

    _Float16* Wt1 = (_Float16*)take((size_t)2 * 49152 * 2);
    _Float16* Wt2 = (_Float16*)take((size_t)2 * 49152 * 2);
    _Float16* Wt3 = (_Float16*)take((size_t)2 * 24576 * 2);

    int*       cnt  = (int*)      take((size_t)N * 4);
    int*       rp   = (int*)      take((size_t)(N + 1) * 4);
    long long* pack = (long long*)take((size_t)2 * E * 8);
    int*       bincur = (int*)    take(MAXB * 4);

    long long*      stage = (long long*)hc;
    unsigned short* soff  = (unsigned short*)((char*)hc + (size_t)2 * E * 8);

    dim3 blk(256);
    const int gN   = (N + 255) / 256;
    const int gE2  = (2 * E + 255) / 256;
    const int gBF  = (2 * E + EPB - 1) / EPB;
    const int gRT  = (N + 63) / 64;
    dim3 gg3_128(gRT, 2);
    dim3 gg3_40(gRT, 1);
    dim3 gg16((N + 15) / 16);

    // ---- W preprocessing: single launch, 3 layers ----
    wsplit_all<<<dim3((49152 + 255) / 256, 3), blk, 0, stream>>>(
        W_ln1, W_c11, W_c21, W_ln2, W_c12, W_c22, W_ln3, W_c13, W_c23, Wt1, Wt2, Wt3);

    // ---- build combined CSR (4 launches) ----
    zero_i32<<<gN, blk, 0, stream>>>(cnt, N);
    hist_c<<<gE2, blk, 0, stream>>>(ei1, ei2, E, cnt);
    scan_all<<<1, blk, 0, stream>>>(cnt, N, rp, nbins, bincur);
    binfill<<<gBF, blk, 0, stream>>>(ei1, ew1, ei2, ew2, E, N, nbins, bincur, stage, soff);
    binplace<<<nbins * 2, blk, 0, stream>>>(stage, soff, rp, N, cnt, pack);

    // ---- Block 1: x -> xA ----
    gemm3<2><<<gg3_128, blk, 0, stream>>>(x, Wt1, b_ln1, b_c11, b_c21, xA, hc, hc + (size_t)N * 128, 128, N);
    gather_c128<<<gg16, blk, 0, stream>>>(hc, rp, pack, xA, N);

    // ---- Block 2: xA -> xB ----
    gemm3<2><<<gg3_128, blk, 0, stream>>>(xA, Wt2, b_ln2, b_c12, b_c22, xB, hc, hc + (size_t)N * 128, 128, N);
    gather_c128<<<gg16, blk, 0, stream>>>(hc, rp, pack, xB, N);

    // ---- Block 3: xB -> xA (width 40), then fused gather+log_softmax -> d_out ----
    gemm3<1><<<gg3_40, blk, 0, stream>>>(xB, Wt3, b_ln3, b_c13, b_c23, xA, hc, hc + (size_t)N * 40, 40, N);
    gather_ls40<<<gg16, blk, 0, stream>>>(hc, rp, pack, xA, (float*)d_out, N);
}

// Round 17
// 347.441 us; speedup vs baseline: 1.3135x; 1.3135x over previous
//
#include <hip/hip_runtime.h>
#include <math.h>

typedef _Float16 f16x8 __attribute__((ext_vector_type(8)));
typedef _Float16 f16x4 __attribute__((ext_vector_type(4)));
typedef float    f32x4 __attribute__((ext_vector_type(4)));

// XOR-swizzled index into a [rows][128] f16 LDS tile (256B rows, no pad).
__device__ __forceinline__ int swz(int row, int k)
{
    return row * 128 + (k ^ ((row & 15) << 3));
}

// ---------------- W preprocess: fragment-major, ALL 3 layers in one launch ----------------
__global__ void wsplit_all(const float* __restrict__ Wa0, const float* __restrict__ Wa1,
                           const float* __restrict__ Wa2, const float* __restrict__ Wb0,
                           const float* __restrict__ Wb1, const float* __restrict__ Wb2,
                           const float* __restrict__ Wc0, const float* __restrict__ Wc1,
                           const float* __restrict__ Wc2,
                           _Float16* __restrict__ D1, _Float16* __restrict__ D2,
                           _Float16* __restrict__ D3)
{
    int layer = blockIdx.y;
    int CHN = (layer == 2) ? 1 : 2;
    int M   = (layer == 2) ? 40 : 128;
    _Float16* dst = (layer == 0) ? D1 : ((layer == 1) ? D2 : D3);
    int total = 3 * CHN * 2 * 2 * 4 * 512;
    int idx = blockIdx.x * 256 + threadIdx.x;
    if (idx >= total) return;
    int e    = idx & 7;
    int lane = (idx >> 3) & 63;
    int kk   = (idx >> 9) & 3;
    int n    = (idx >> 11) & 1;
    int wc   = (idx >> 12) & 1;
    int rest = idx >> 13;
    int ch   = rest % CHN;
    int br   = rest / CHN;
    int col  = ch * 64 + wc * 32 + n * 16 + (lane & 15);
    int k    = kk * 32 + (lane >> 4) * 8 + e;
    const float* W;
    if (layer == 0)      W = (br == 0) ? Wa0 : ((br == 1) ? Wa1 : Wa2);
    else if (layer == 1) W = (br == 0) ? Wb0 : ((br == 1) ? Wb1 : Wb2);
    else                 W = (br == 0) ? Wc0 : ((br == 1) ? Wc1 : Wc2);
    float v = (col < M) ? W[(size_t)k * M + col] : 0.f;
    _Float16 h = (_Float16)v;
    dst[idx] = h;
    dst[total + idx] = (_Float16)(v - (float)h);
}

// ---------------- split-f16 MFMA GEMM: X in swizzled LDS, W fragment-coalesced from L2 ----
template<int CHN>
__global__ __launch_bounds__(256)
void gemm3(const float* __restrict__ X, const _Float16* __restrict__ Wf,
           const float* __restrict__ b0, const float* __restrict__ b1,
           const float* __restrict__ b2,
           float* __restrict__ out0, _Float16* __restrict__ out1, _Float16* __restrict__ out2,
           int M, int nrows)
{
    __shared__ _Float16 xh[64 * 128], xl[64 * 128];   // 32 KB total

    const int tid  = threadIdx.x;
    const int row0 = blockIdx.x * 64;
    const int ch   = blockIdx.y;
    const int plane = 3 * CHN * 2 * 2 * 4 * 512;

    float4 xr[8];
    #pragma unroll
    for (int i = 0; i < 8; ++i) {
        int idx = tid + i * 256;
        int row = idx >> 5;
        int k   = (idx & 31) * 4;
        int gr  = row0 + row;
        xr[i] = (gr < nrows) ? *(const float4*)(X + (size_t)gr * 128 + k)
                             : make_float4(0.f, 0.f, 0.f, 0.f);
    }
    #pragma unroll
    for (int i = 0; i < 8; ++i) {
        int idx = tid + i * 256;
        int row = idx >> 5;
        int k   = (idx & 31) * 4;
        float vv[4] = {xr[i].x, xr[i].y, xr[i].z, xr[i].w};
        f16x4 h, l;
        #pragma unroll
        for (int j = 0; j < 4; ++j) {
            _Float16 hj = (_Float16)vv[j];
            h[j] = hj;
            l[j] = (_Float16)(vv[j] - (float)hj);
        }
        int o = swz(row, k);
        *(f16x4*)&xh[o] = h;
        *(f16x4*)&xl[o] = l;
    }
    __syncthreads();

    const int lane = tid & 63;
    const int wid  = tid >> 6;
    const int wr   = wid >> 1, wc = wid & 1;
    const int r    = lane & 15, g = lane >> 4;

    f16x8 Ah[2][4], Al[2][4];
    #pragma unroll
    for (int m = 0; m < 2; ++m)
        #pragma unroll
        for (int kk = 0; kk < 4; ++kk) {
            int o = swz(wr * 32 + m * 16 + r, kk * 32 + g * 8);
            Ah[m][kk] = *(const f16x8*)&xh[o];
            Al[m][kk] = *(const f16x8*)&xl[o];
        }

    #pragma unroll
    for (int br = 0; br < 3; ++br) {
        f32x4 acc[2][2];
        #pragma unroll
        for (int m = 0; m < 2; ++m)
            #pragma unroll
            for (int n = 0; n < 2; ++n)
                acc[m][n] = (f32x4){0.f, 0.f, 0.f, 0.f};

        #pragma unroll
        for (int n = 0; n < 2; ++n) {
            size_t fb = ((((size_t)(br * CHN + ch) * 2 + wc) * 2 + n) * 4) * 512 + lane * 8;
            f16x8 Bh[4], Bl[4];
            #pragma unroll
            for (int kk = 0; kk < 4; ++kk) {
                Bh[kk] = *(const f16x8*)&Wf[fb + kk * 512];
                Bl[kk] = *(const f16x8*)&Wf[plane + fb + kk * 512];
            }
            #pragma unroll
            for (int kk = 0; kk < 4; ++kk) {
                #pragma unroll
                for (int m = 0; m < 2; ++m) {
                    acc[m][n] = __builtin_amdgcn_mfma_f32_16x16x32_f16(Ah[m][kk], Bh[kk], acc[m][n], 0, 0, 0);
                    acc[m][n] = __builtin_amdgcn_mfma_f32_16x16x32_f16(Ah[m][kk], Bl[kk], acc[m][n], 0, 0, 0);
                    acc[m][n] = __builtin_amdgcn_mfma_f32_16x16x32_f16(Al[m][kk], Bh[kk], acc[m][n], 0, 0, 0);
                }
            }
        }

        #pragma unroll
        for (int m = 0; m < 2; ++m)
            #pragma unroll
            for (int n = 0; n < 2; ++n) {
                int col = ch * 64 + wc * 32 + n * 16 + r;
                if (col >= M) continue;
                if (br == 0) {
                    float bs = b0[col] + b1[col] + b2[col];
                    #pragma unroll
                    for (int i = 0; i < 4; ++i) {
                        int row = row0 + wr * 32 + m * 16 + g * 4 + i;
                        if (row < nrows)
                            out0[(size_t)row * M + col] = acc[m][n][i] + bs;
                    }
                } else {
                    _Float16* outp = (br == 1) ? out1 : out2;
                    #pragma unroll
                    for (int i = 0; i < 4; ++i) {
                        int row = row0 + wr * 32 + m * 16 + g * 4 + i;
                        if (row < nrows)
                            outp[(size_t)row * M + col] = (_Float16)acc[m][n][i];
                    }
                }
            }
    }
}

// ---------------- combined CSR build over both edge sets (2E edges) ----------------
__global__ void zero_i32(int* __restrict__ p, int n)
{
    int i = blockIdx.x * 256 + threadIdx.x;
    if (i < n) p[i] = 0;
}

__global__ void hist_c(const int* __restrict__ ei1, const int* __restrict__ ei2,
                       int E, int* __restrict__ cnt)
{
    int i = blockIdx.x * 256 + threadIdx.x;
    if (i >= 2 * E) return;
    int d = (i < E) ? ei1[E + i] : ei2[E + (i - E)];
    atomicAdd(&cnt[d], 1);
}

__global__ void scan_phase1(const int* __restrict__ cnt, int ncnt, int* __restrict__ bsums, int n)
{
    __shared__ int s[256];
    int tid = threadIdx.x;
    int i = blockIdx.x * 256 + tid;
    int v = (i < n && i < ncnt) ? cnt[i] : 0;
    s[tid] = v; __syncthreads();
    for (int off = 128; off; off >>= 1) {
        if (tid < off) s[tid] += s[tid + off];
        __syncthreads();
    }
    if (tid == 0) bsums[blockIdx.x] = s[0];
}

__global__ void scan_phase2(int* __restrict__ bsums, int nb)
{
    __shared__ int s[256];
    int tid = threadIdx.x;
    int v = (tid < nb) ? bsums[tid] : 0;
    s[tid] = v; __syncthreads();
    for (int off = 1; off < 256; off <<= 1) {
        int t = (tid >= off) ? s[tid - off] : 0;
        __syncthreads();
        s[tid] += t;
        __syncthreads();
    }
    if (tid < nb) bsums[tid] = s[tid] - v;   // exclusive
}

// also zeroes cnt (reused as fill cursor in binplace)
__global__ void scan_phase3(int* __restrict__ cnt, int ncnt,
                            const int* __restrict__ bsums, int* __restrict__ row_ptr, int n)
{
    __shared__ int s[256];
    int tid = threadIdx.x;
    int i = blockIdx.x * 256 + tid;
    int v = (i < n && i < ncnt) ? cnt[i] : 0;
    s[tid] = v; __syncthreads();
    for (int off = 1; off < 256; off <<= 1) {
        int t = (tid >= off) ? s[tid - off] : 0;
        __syncthreads();
        s[tid] += t;
        __syncthreads();
    }
    if (i < n) {
        row_ptr[i] = s[tid] - v + bsums[blockIdx.x];
        if (i < ncnt) cnt[i] = 0;
    }
}

__global__ void init_bincur(const int* __restrict__ rp, int N, int nbins, int* __restrict__ bincur)
{
    int b = blockIdx.x * 256 + threadIdx.x;
    if (b < nbins) {
        int r = b << 9;
        bincur[b] = rp[r < N ? r : N];
    }
}

// ---------------- phase C: bin-bucketed staging of edge records ----------------
constexpr int EPB  = 2048;
constexpr int MAXB = 128;

__global__ __launch_bounds__(256)
void binfill(const int* __restrict__ ei1, const float* __restrict__ ew1,
             const int* __restrict__ ei2, const float* __restrict__ ew2,
             int E, int N, int nbins, int* __restrict__ bincur,
             long long* __restrict__ stage, unsigned short* __restrict__ soff)
{
    __shared__ int hist[MAXB];
    __shared__ int scanb[MAXB];
    __shared__ int gbase[MAXB];
    __shared__ long long srec[EPB];
    __shared__ unsigned short sdo[EPB];
    __shared__ unsigned char  sbin[EPB];

    const int t = threadIdx.x;
    const long long base = (long long)blockIdx.x * EPB;
    int total = 2 * E - (int)base; if (total > EPB) total = EPB;

    for (int i = t; i < MAXB; i += 256) hist[i] = 0;
    __syncthreads();

    int myb[8], myr[8], myo[8];
    long long myrec[8];
    #pragma unroll
    for (int k = 0; k < 8; ++k) {
        int i = t + k * 256;
        myb[k] = -1;
        if (i < total) {
            int j = (int)(base + i);
            int set = (j >= E);
            int e = set ? j - E : j;
            const int* ei = set ? ei2 : ei1;
            int d = ei[E + e];
            int s = ei[e] + (set ? N : 0);
            float w = set ? ew2[e] : ew1[e];
            myb[k] = d >> 9;
            myo[k] = d & 511;
            myrec[k] = ((long long)__float_as_int(w) << 32) | (unsigned)s;
            myr[k] = atomicAdd(&hist[myb[k]], 1);
        }
    }
    __syncthreads();

    if (t < MAXB) scanb[t] = hist[t];
    __syncthreads();
    for (int off = 1; off < MAXB; off <<= 1) {
        int tv = 0;
        if (t < MAXB && t >= off) tv = scanb[t - off];
        __syncthreads();
        if (t < MAXB) scanb[t] += tv;
        __syncthreads();
    }
    if (t < nbins && hist[t] > 0)
        gbase[t] = atomicAdd(&bincur[t], hist[t]);
    __syncthreads();

    #pragma unroll
    for (int k = 0; k < 8; ++k) {
        if (myb[k] >= 0) {
            int slot = scanb[myb[k]] - hist[myb[k]] + myr[k];
            srec[slot] = myrec[k];
            sdo[slot]  = (unsigned short)myo[k];
            sbin[slot] = (unsigned char)myb[k];
        }
    }
    __syncthreads();

    #pragma unroll
    for (int k = 0; k < 8; ++k) {
        int i = t + k * 256;
        if (i < total) {
            int b = sbin[i];
            int addr = gbase[b] + (i - (scanb[b] - hist[b]));
            stage[addr] = srec[i];
            soff[addr]  = sdo[i];
        }
    }
}

// ---------------- phase D: within-bin scatter to final CSR slots (L2-local) ----------------
__global__ __launch_bounds__(256)
void binplace(const long long* __restrict__ stage, const unsigned short* __restrict__ soff,
              const int* __restrict__ rp, int N, int* __restrict__ cur,
              long long* __restrict__ pack)
{
    int bin  = blockIdx.x >> 1;
    int half = blockIdx.x & 1;
    int r0 = bin << 9;
    int r1 = r0 + 512; if (r1 > N) r1 = N;
    if (r0 >= N) return;
    int beg = rp[r0], end = rp[r1];
    int mid = beg + ((end - beg + 1) >> 1);
    int lo = half ? mid : beg;
    int hi = half ? end : mid;
    for (int i = lo + threadIdx.x; i < hi; i += 256) {
        long long rec = stage[i];
        int d = r0 + soff[i];
        int p = rp[d] + atomicAdd(&cur[d], 1);
        pack[p] = rec;
    }
}

// ---------------- gather (width 128), 16 lanes/row, f16x8, 4-deep MLP ----------------
__global__ __launch_bounds__(256)
void gather_c128(const _Float16* __restrict__ hc, const int* __restrict__ rp,
                 const long long* __restrict__ pack, float* __restrict__ out, int N)
{
    int row = blockIdx.x * 16 + (threadIdx.x >> 4);
    if (row >= N) return;
    int lane = threadIdx.x & 15;
    int beg = rp[row], end = rp[row + 1];
    float* o = out + (size_t)row * 128 + lane * 8;
    float4 c0 = *(const float4*)o;
    float4 c1 = *(const float4*)(o + 4);
    float a[8] = {};
    int i = beg;
    for (; i + 4 <= end; i += 4) {
        long long q0 = __builtin_nontemporal_load(&pack[i]);
        long long q1 = __builtin_nontemporal_load(&pack[i + 1]);
        long long q2 = __builtin_nontemporal_load(&pack[i + 2]);
        long long q3 = __builtin_nontemporal_load(&pack[i + 3]);
        f16x8 v0 = *(const f16x8*)(hc + (size_t)(unsigned)q0 * 128 + lane * 8);
        f16x8 v1 = *(const f16x8*)(hc + (size_t)(unsigned)q1 * 128 + lane * 8);
        f16x8 v2 = *(const f16x8*)(hc + (size_t)(unsigned)q2 * 128 + lane * 8);
        f16x8 v3 = *(const f16x8*)(hc + (size_t)(unsigned)q3 * 128 + lane * 8);
        float w0 = __int_as_float((int)(q0 >> 32));
        float w1 = __int_as_float((int)(q1 >> 32));
        float w2 = __int_as_float((int)(q2 >> 32));
        float w3 = __int_as_float((int)(q3 >> 32));
        #pragma unroll
        for (int j = 0; j < 8; ++j) {
            a[j] = fmaf(w0, (float)v0[j], a[j]);
            a[j] = fmaf(w1, (float)v1[j], a[j]);
            a[j] = fmaf(w2, (float)v2[j], a[j]);
            a[j] = fmaf(w3, (float)v3[j], a[j]);
        }
    }
    for (; i < end; ++i) {
        long long q0 = __builtin_nontemporal_load(&pack[i]);
        f16x8 v0 = *(const f16x8*)(hc + (size_t)(unsigned)q0 * 128 + lane * 8);
        float w0 = __int_as_float((int)(q0 >> 32));
        #pragma unroll
        for (int j = 0; j < 8; ++j) a[j] = fmaf(w0, (float)v0[j], a[j]);
    }
    c0.x += a[0]; c0.y += a[1]; c0.z += a[2]; c0.w += a[3];
    c1.x += a[4]; c1.y += a[5]; c1.z += a[6]; c1.w += a[7];
    *(float4*)o = c0;
    *(float4*)(o + 4) = c1;
}

// ---------------- final: gather (width 40) + log_softmax fused ----------------
__global__ __launch_bounds__(256)
void gather_ls40(const _Float16* __restrict__ hc, const int* __restrict__ rp,
                 const long long* __restrict__ pack, const float* __restrict__ xlin,
                 float* __restrict__ out, int N)
{
    int row = blockIdx.x * 16 + (threadIdx.x >> 4);
    int lane = threadIdx.x & 15;
    if (row >= N) return;
    bool act = (lane < 10);

    float v0 = -INFINITY, v1 = -INFINITY, v2 = -INFINITY, v3 = -INFINITY;
    if (act) {
        float a0 = 0.f, a1 = 0.f, a2 = 0.f, a3 = 0.f;
        int beg = rp[row], end = rp[row + 1];
        int i = beg;
        for (; i + 4 <= end; i += 4) {
            long long q0 = __builtin_nontemporal_load(&pack[i]);
            long long q1 = __builtin_nontemporal_load(&pack[i + 1]);
            long long q2 = __builtin_nontemporal_load(&pack[i + 2]);
            long long q3 = __builtin_nontemporal_load(&pack[i + 3]);
            f16x4 va = *(const f16x4*)(hc + (size_t)(unsigned)q0 * 40 + lane * 4);
            f16x4 vb = *(const f16x4*)(hc + (size_t)(unsigned)q1 * 40 + lane * 4);
            f16x4 vc = *(const f16x4*)(hc + (size_t)(unsigned)q2 * 40 + lane * 4);
            f16x4 vd = *(const f16x4*)(hc + (size_t)(unsigned)q3 * 40 + lane * 4);
            float wa = __int_as_float((int)(q0 >> 32));
            float wb = __int_as_float((int)(q1 >> 32));
            float wc = __int_as_float((int)(q2 >> 32));
            float wd = __int_as_float((int)(q3 >> 32));
            a0 = fmaf(wa, (float)va[0], a0); a1 = fmaf(wa, (float)va[1], a1);
            a2 = fmaf(wa, (float)va[2], a2); a3 = fmaf(wa, (float)va[3], a3);
            a0 = fmaf(wb, (float)vb[0], a0); a1 = fmaf(wb, (float)vb[1], a1);
            a2 = fmaf(wb, (float)vb[2], a2); a3 = fmaf(wb, (float)vb[3], a3);
            a0 = fmaf(wc, (float)vc[0], a0); a1 = fmaf(wc, (float)vc[1], a1);
            a2 = fmaf(wc, (float)vc[2], a2); a3 = fmaf(wc, (float)vc[3], a3);
            a0 = fmaf(wd, (float)vd[0], a0); a1 = fmaf(wd, (float)vd[1], a1);
            a2 = fmaf(wd, (float)vd[2], a2); a3 = fmaf(wd, (float)vd[3], a3);
        }
        for (; i < end; ++i) {
            long long q0 = __builtin_nontemporal_load(&pack[i]);
            f16x4 va = *(const f16x4*)(hc + (size_t)(unsigned)q0 * 40 + lane * 4);
            float wa = __int_as_float((int)(q0 >> 32));
            a0 = fmaf(wa, (float)va[0], a0); a1 = fmaf(wa, (float)va[1], a1);
            a2 = fmaf(wa, (float)va[2], a2); a3 = fmaf(wa, (float)va[3], a3);
        }
        float4 c = *(const float4*)(xlin + (size_t)row * 40 + lane * 4);
        v0 = c.x + a0; v1 = c.y + a1; v2 = c.z + a2; v3 = c.w + a3;
    }

    float m = fmaxf(fmaxf(v0, v1), fmaxf(v2, v3));
    #pragma unroll
    for (int off = 8; off; off >>= 1) m = fmaxf(m, __shfl_xor(m, off, 16));
    float s = 0.f;
    if (act) s = expf(v0 - m) + expf(v1 - m) + expf(v2 - m) + expf(v3 - m);
    #pragma unroll
    for (int off = 8; off; off >>= 1) s += __shfl_xor(s, off, 16);
    float ls = m + logf(s);

    if (act) {
        float* o = out + (size_t)row * 40 + lane * 4;
        o[0] = v0 - ls; o[1] = v1 - ls; o[2] = v2 - ls; o[3] = v3 - ls;
    }
}

// ---------------- launch ----------------
extern "C" void kernel_launch(void* const* d_in, const int* in_sizes, int n_in,
                              void* d_out, int out_size, void* d_ws, size_t ws_size,
                              hipStream_t stream)
{
    const float* x    = (const float*)d_in[0];
    const int*   ei1  = (const int*)  d_in[1];
    const float* ew1  = (const float*)d_in[2];
    const int*   ei2  = (const int*)  d_in[3];
    const float* ew2  = (const float*)d_in[4];

    const float* W_ln1 = (const float*)d_in[5];   const float* b_ln1 = (const float*)d_in[6];
    const float* W_c11 = (const float*)d_in[7];   const float* b_c11 = (const float*)d_in[8];
    const float* W_c21 = (const float*)d_in[9];   const float* b_c21 = (const float*)d_in[10];
    const float* W_ln2 = (const float*)d_in[11];  const float* b_ln2 = (const float*)d_in[12];
    const float* W_c12 = (const float*)d_in[13];  const float* b_c12 = (const float*)d_in[14];
    const float* W_c22 = (const float*)d_in[15];  const float* b_c22 = (const float*)d_in[16];
    const float* W_ln3 = (const float*)d_in[17];  const float* b_ln3 = (const float*)d_in[18];
    const float* W_c13 = (const float*)d_in[19];  const float* b_c13 = (const float*)d_in[20];
    const float* W_c23 = (const float*)d_in[21];  const float* b_c23 = (const float*)d_in[22];

    const int N = in_sizes[0] / 128;   // 50000
    const int E = in_sizes[2];         // 600000
    const int nbins = (N + 511) >> 9;  // 98

    // ---- workspace layout ----
    auto align_up = [](size_t v) { return (v + 255) & ~(size_t)255; };
    char* base = (char*)d_ws;
    size_t off = 0;
    auto take = [&](size_t bytes) { char* p = base + off; off += align_up(bytes); return p; };

    float*     xA   = (float*)    take((size_t)N * 128 * 4);
    float*     xB   = (float*)    take((size_t)N * 128 * 4);
    _Float16*  hc   = (_Float16*) take((size_t)2 * N * 128 * 2);

    _Float16* Wt1 = (_Float16*)take((size_t)2 * 49152 * 2);
    _Float16* Wt2 = (_Float16*)take((size_t)2 * 49152 * 2);
    _Float16* Wt3 = (_Float16*)take((size_t)2 * 24576 * 2);

    int*       cnt  = (int*)      take((size_t)N * 4);
    int*       rp   = (int*)      take((size_t)(N + 1) * 4);
    long long* pack = (long long*)take((size_t)2 * E * 8);
    int*       bs   = (int*)      take(256 * 4);
    int*       bincur = (int*)    take(MAXB * 4);

    long long*      stage = (long long*)hc;
    unsigned short* soff  = (unsigned short*)((char*)hc + (size_t)2 * E * 8);

    dim3 blk(256);
    const int gN   = (N + 255) / 256;
    const int gN1  = (N + 1 + 255) / 256;
    const int gE2  = (2 * E + 255) / 256;
    const int gBF  = (2 * E + EPB - 1) / EPB;
    const int gRT  = (N + 63) / 64;
    dim3 gg3_128(gRT, 2);
    dim3 gg3_40(gRT, 1);
    dim3 gg16((N + 15) / 16);

    // ---- W preprocessing: single launch, 3 layers ----
    wsplit_all<<<dim3((49152 + 255) / 256, 3), blk, 0, stream>>>(
        W_ln1, W_c11, W_c21, W_ln2, W_c12, W_c22, W_ln3, W_c13, W_c23, Wt1, Wt2, Wt3);

    // ---- build combined CSR ----
    zero_i32<<<gN, blk, 0, stream>>>(cnt, N);
    hist_c<<<gE2, blk, 0, stream>>>(ei1, ei2, E, cnt);
    scan_phase1<<<gN1, blk, 0, stream>>>(cnt, N, bs, N + 1);
    scan_phase2<<<1, blk, 0, stream>>>(bs, gN1);
    scan_phase3<<<gN1, blk, 0, stream>>>(cnt, N, bs, rp, N + 1);
    init_bincur<<<1, blk, 0, stream>>>(rp, N, nbins, bincur);
    binfill<<<gBF, blk, 0, stream>>>(ei1, ew1, ei2, ew2, E, N, nbins, bincur, stage, soff);
    binplace<<<nbins * 2, blk, 0, stream>>>(stage, soff, rp, N, cnt, pack);

    // ---- Block 1: x -> xA ----
    gemm3<2><<<gg3_128, blk, 0, stream>>>(x, Wt1, b_ln1, b_c11, b_c21, xA, hc, hc + (size_t)N * 128, 128, N);
    gather_c128<<<gg16, blk, 0, stream>>>(hc, rp, pack, xA, N);

    // ---- Block 2: xA -> xB ----
    gemm3<2><<<gg3_128, blk, 0, stream>>>(xA, Wt2, b_ln2, b_c12, b_c22, xB, hc, hc + (size_t)N * 128, 128, N);
    gather_c128<<<gg16, blk, 0, stream>>>(hc, rp, pack, xB, N);

    // ---- Block 3: xB -> xA (width 40), then fused gather+log_softmax -> d_out ----
    gemm3<1><<<gg3_40, blk, 0, stream>>>(xB, Wt3, b_ln3, b_c13, b_c23, xA, hc, hc + (size_t)N * 40, 40, N);
    gather_ls40<<<gg16, blk, 0, stream>>>(hc, rp, pack, xA, (float*)d_out, N);
}